// Round 1
// baseline (298.971 us; speedup 1.0000x reference)
//
#include <hip/hip_runtime.h>
#include <hip/hip_bf16.h>
#include <cstdint>

// Problem constants
#define BATCH 4096
#define DIN   512
#define DH    256
#define DG    128
#define NH    8
#define NTOT  3328   // DH + NH*DH + NH*DG = 256 + 2048 + 1024

typedef __bf16 bf16x8 __attribute__((ext_vector_type(8)));
typedef float  f32x4  __attribute__((ext_vector_type(4)));

__device__ __forceinline__ unsigned short f2bf(float f) {
    union { float f; uint32_t u; } v; v.f = f;
    uint32_t u = v.u;
    u += 0x7fffu + ((u >> 16) & 1u);   // RNE; inputs are finite normals
    return (unsigned short)(u >> 16);
}

// ---------------- prep: x (4096x512 f32) -> bf16 ----------------
__global__ void cvt_x(const float* __restrict__ x, unsigned short* __restrict__ xb) {
    int i = (blockIdx.x * 256 + threadIdx.x) * 4;
    float4 v = *(const float4*)(x + i);
    ushort4 o;
    o.x = f2bf(v.x); o.y = f2bf(v.y); o.z = f2bf(v.z); o.w = f2bf(v.w);
    *(ushort4*)(xb + i) = o;
}

// ---- prep: transpose/concat Wh,Wz1,Wz2 (K x n) -> Wt[3328][512] bf16 ----
__global__ void transpose_w(const float* __restrict__ Wh, const float* __restrict__ Wz1,
                            const float* __restrict__ Wz2, unsigned short* __restrict__ Wt) {
    __shared__ float tile[32][33];
    int n0 = blockIdx.x * 32;   // global output-channel tile (0..3327)
    int k0 = blockIdx.y * 32;
    const float* W; int ldn, nl;
    if (n0 < 256)       { W = Wh;  ldn = 256;  nl = n0; }
    else if (n0 < 2304) { W = Wz1; ldn = 2048; nl = n0 - 256; }
    else                { W = Wz2; ldn = 1024; nl = n0 - 2304; }
    int tx = threadIdx.x, ty = threadIdx.y;   // 32 x 8
    #pragma unroll
    for (int i = 0; i < 4; i++) {
        int kk = ty + i * 8;
        tile[kk][tx] = W[(size_t)(k0 + kk) * ldn + nl + tx];   // coalesced read along n
    }
    __syncthreads();
    #pragma unroll
    for (int i = 0; i < 4; i++) {
        int nn = ty + i * 8;
        Wt[(size_t)(n0 + nn) * 512 + k0 + tx] = f2bf(tile[tx][nn]);  // coalesced write along k
    }
}

// ------------- fused GEMM: Z[4096][3328] = xb @ Wt^T (bf16 MFMA) -------------
// 128x128 tile, 4 waves of 64x64, BK=32, LDS rows padded to 40 bf16 (2-way = free)
__global__ __launch_bounds__(256) void gemm_kernel(const unsigned short* __restrict__ xb,
                                                   const unsigned short* __restrict__ Wt,
                                                   float* __restrict__ Z) {
    __shared__ unsigned short As[128 * 40];
    __shared__ unsigned short Bs[128 * 40];
    const int m0 = blockIdx.y * 128;
    const int n0 = blockIdx.x * 128;
    const int t = threadIdx.x;
    const int w = t >> 6, lane = t & 63;
    const int wm = (w >> 1) * 64, wn = (w & 1) * 64;
    const int lrow = lane & 15, q = lane >> 4;

    f32x4 acc[4][4] = {};

    for (int k0 = 0; k0 < DIN; k0 += 32) {
        __syncthreads();
        #pragma unroll
        for (int r = 0; r < 2; r++) {
            int idx = r * 256 + t;
            int row = idx >> 2, ch = idx & 3;          // 64B row = 4 x 16B chunks
            uint4 va = *(const uint4*)(xb + (size_t)(m0 + row) * DIN + k0 + ch * 8);
            uint4 vb = *(const uint4*)(Wt + (size_t)(n0 + row) * DIN + k0 + ch * 8);
            *(uint4*)(As + row * 40 + ch * 8) = va;
            *(uint4*)(Bs + row * 40 + ch * 8) = vb;
        }
        __syncthreads();
        bf16x8 af[4], bfr[4];
        #pragma unroll
        for (int i = 0; i < 4; i++)
            af[i] = *reinterpret_cast<const bf16x8*>(As + (wm + i * 16 + lrow) * 40 + q * 8);
        #pragma unroll
        for (int j = 0; j < 4; j++)
            bfr[j] = *reinterpret_cast<const bf16x8*>(Bs + (wn + j * 16 + lrow) * 40 + q * 8);
        #pragma unroll
        for (int i = 0; i < 4; i++)
            #pragma unroll
            for (int j = 0; j < 4; j++)
                acc[i][j] = __builtin_amdgcn_mfma_f32_16x16x32_bf16(af[i], bfr[j], acc[i][j], 0, 0, 0);
    }
    // C/D layout: col = lane&15, row = (lane>>4)*4 + reg   [verified m89/m91]
    #pragma unroll
    for (int i = 0; i < 4; i++)
        #pragma unroll
        for (int j = 0; j < 4; j++) {
            int col = n0 + wn + j * 16 + lrow;
            int rbase = m0 + wm + i * 16 + q * 4;
            #pragma unroll
            for (int r = 0; r < 4; r++)
                Z[(size_t)(rbase + r) * NTOT + col] = acc[i][j][r];
        }
}

__device__ __forceinline__ float tanh_fast(float x) {
    float xc = fminf(fmaxf(x, -20.0f), 20.0f);
    float e = __expf(2.0f * xc);                      // v_exp_f32 path
    return 1.0f - 2.0f * __builtin_amdgcn_rcpf(e + 1.0f);
}

// ------- per-batch: LN(relu(hpre+b)) -> h ; w = z2^T z1 ; standardize+tanh ; y = w h -------
__global__ __launch_bounds__(256) void attn_kernel(const float* __restrict__ Z,
                                                   const float* __restrict__ bh,
                                                   const float* __restrict__ lns,
                                                   const float* __restrict__ lnb,
                                                   float* __restrict__ h_out,
                                                   float* __restrict__ y_out) {
    __shared__ float z1s[NH * DH];   // 8KB
    __shared__ float z2s[NH * DG];   // 4KB
    __shared__ float hs[DH];         // 1KB
    __shared__ float red[4][2];
    const int b = blockIdx.x;
    const int t = threadIdx.x;
    const float* Zrow = Z + (size_t)b * NTOT;

    // stage z1 (2048 f32) and z2 (1024 f32) into LDS
    {
        float4 v0 = *(const float4*)(Zrow + DH + t * 4);
        float4 v1 = *(const float4*)(Zrow + DH + 1024 + t * 4);
        float4 v2 = *(const float4*)(Zrow + DH + 2048 + t * 4);
        *(float4*)(z1s + t * 4) = v0;
        *(float4*)(z1s + 1024 + t * 4) = v1;
        *(float4*)(z2s + t * 4) = v2;
    }
    // layernorm(relu(hpre + bh)) over 256 elems, one per thread
    float v = fmaxf(Zrow[t] + bh[t], 0.0f);
    float s = v, sq = v * v;
    #pragma unroll
    for (int m = 32; m >= 1; m >>= 1) {
        s  += __shfl_xor(s,  m, 64);
        sq += __shfl_xor(sq, m, 64);
    }
    int wave = t >> 6;
    if ((t & 63) == 0) { red[wave][0] = s; red[wave][1] = sq; }
    __syncthreads();   // also makes z1s/z2s visible
    s  = red[0][0] + red[1][0] + red[2][0] + red[3][0];
    sq = red[0][1] + red[1][1] + red[2][1] + red[3][1];
    float mu  = s * (1.0f / 256.0f);
    float var = sq * (1.0f / 256.0f) - mu * mu;
    float hval = (v - mu) * rsqrtf(var + 1e-6f) * lns[t] + lnb[t];
    hs[t] = hval;
    h_out[(size_t)b * DH + t] = hval;

    // thread tile: 8 g-rows x 16 d-cols; td picks interleaved d chunks (conflict-free)
    const int td = t & 15, tg = t >> 4;
    const int g0 = tg * 8;
    float z2r[NH][8];
    #pragma unroll
    for (int hh = 0; hh < NH; hh++) {
        float4 a = *(const float4*)(z2s + hh * DG + g0);
        float4 c = *(const float4*)(z2s + hh * DG + g0 + 4);
        z2r[hh][0]=a.x; z2r[hh][1]=a.y; z2r[hh][2]=a.z; z2r[hh][3]=a.w;
        z2r[hh][4]=c.x; z2r[hh][5]=c.y; z2r[hh][6]=c.z; z2r[hh][7]=c.w;
    }
    // pass 1: row stats of w (recompute pattern, no w storage)
    float sm[8] = {0,0,0,0,0,0,0,0}, sqg[8] = {0,0,0,0,0,0,0,0};
    #pragma unroll
    for (int c = 0; c < 4; c++) {
        int dbase = c * 64 + td * 4;
        float wv[8][4] = {};
        #pragma unroll
        for (int hh = 0; hh < NH; hh++) {
            float4 z1v = *(const float4*)(z1s + hh * DH + dbase);
            #pragma unroll
            for (int gi = 0; gi < 8; gi++) {
                wv[gi][0] += z2r[hh][gi] * z1v.x;
                wv[gi][1] += z2r[hh][gi] * z1v.y;
                wv[gi][2] += z2r[hh][gi] * z1v.z;
                wv[gi][3] += z2r[hh][gi] * z1v.w;
            }
        }
        #pragma unroll
        for (int gi = 0; gi < 8; gi++)
            #pragma unroll
            for (int e = 0; e < 4; e++) {
                sm[gi]  += wv[gi][e];
                sqg[gi] += wv[gi][e] * wv[gi][e];
            }
    }
    // reduce stats across the 16 td-lanes (within-wave)
    #pragma unroll
    for (int m = 1; m <= 8; m <<= 1)
        #pragma unroll
        for (int gi = 0; gi < 8; gi++) {
            sm[gi]  += __shfl_xor(sm[gi],  m, 64);
            sqg[gi] += __shfl_xor(sqg[gi], m, 64);
        }
    float mug[8], invg[8];
    #pragma unroll
    for (int gi = 0; gi < 8; gi++) {
        float m_ = sm[gi] * (1.0f / 256.0f);
        float va = fmaxf(sqg[gi] * (1.0f / 256.0f) - m_ * m_, 0.0f);
        mug[gi] = m_;
        invg[gi] = 1.0f / (sqrtf(va) + 1e-6f);   // matches (w-mu)/(std+eps)
    }
    __syncthreads();   // hs ready for all threads

    // pass 2: recompute w, tanh, dot with h
    float yv[8] = {0,0,0,0,0,0,0,0};
    #pragma unroll
    for (int c = 0; c < 4; c++) {
        int dbase = c * 64 + td * 4;
        float wv[8][4] = {};
        #pragma unroll
        for (int hh = 0; hh < NH; hh++) {
            float4 z1v = *(const float4*)(z1s + hh * DH + dbase);
            #pragma unroll
            for (int gi = 0; gi < 8; gi++) {
                wv[gi][0] += z2r[hh][gi] * z1v.x;
                wv[gi][1] += z2r[hh][gi] * z1v.y;
                wv[gi][2] += z2r[hh][gi] * z1v.z;
                wv[gi][3] += z2r[hh][gi] * z1v.w;
            }
        }
        float4 hv = *(const float4*)(hs + dbase);
        #pragma unroll
        for (int gi = 0; gi < 8; gi++) {
            yv[gi] += tanh_fast((wv[gi][0] - mug[gi]) * invg[gi]) * hv.x;
            yv[gi] += tanh_fast((wv[gi][1] - mug[gi]) * invg[gi]) * hv.y;
            yv[gi] += tanh_fast((wv[gi][2] - mug[gi]) * invg[gi]) * hv.z;
            yv[gi] += tanh_fast((wv[gi][3] - mug[gi]) * invg[gi]) * hv.w;
        }
    }
    #pragma unroll
    for (int m = 1; m <= 8; m <<= 1)
        #pragma unroll
        for (int gi = 0; gi < 8; gi++)
            yv[gi] += __shfl_xor(yv[gi], m, 64);
    if (td == 0) {
        float4 o0 = {yv[0], yv[1], yv[2], yv[3]};
        float4 o1 = {yv[4], yv[5], yv[6], yv[7]};
        *(float4*)(y_out + (size_t)b * DG + g0)     = o0;
        *(float4*)(y_out + (size_t)b * DG + g0 + 4) = o1;
    }
}

extern "C" void kernel_launch(void* const* d_in, const int* in_sizes, int n_in,
                              void* d_out, int out_size, void* d_ws, size_t ws_size,
                              hipStream_t stream) {
    const float* x   = (const float*)d_in[0];
    const float* Wh  = (const float*)d_in[1];
    const float* bh  = (const float*)d_in[2];
    const float* Wz1 = (const float*)d_in[3];
    const float* Wz2 = (const float*)d_in[4];
    const float* lns = (const float*)d_in[5];
    const float* lnb = (const float*)d_in[6];
    float* h_out = (float*)d_out;
    float* y_out = h_out + (size_t)BATCH * DH;

    char* ws = (char*)d_ws;
    float*          Z  = (float*)ws;                        // 4096*3328*4 = 54,525,952 B
    unsigned short* xb = (unsigned short*)(ws + 54525952);  // 4096*512*2  =  4,194,304 B
    unsigned short* Wt = (unsigned short*)(ws + 58720256);  // 3328*512*2  =  3,407,872 B (total ~62.1 MB)

    cvt_x      <<<2048, 256, 0, stream>>>(x, xb);
    transpose_w<<<dim3(104, 16), dim3(32, 8), 0, stream>>>(Wh, Wz1, Wz2, Wt);
    gemm_kernel<<<dim3(NTOT / 128, BATCH / 128), 256, 0, stream>>>(xb, Wt, Z);
    attn_kernel<<<BATCH, 256, 0, stream>>>(Z, bh, lns, lnb, h_out, y_out);
}

// Round 2
// 194.851 us; speedup vs baseline: 1.5344x; 1.5344x over previous
//
#include <hip/hip_runtime.h>
#include <hip/hip_bf16.h>
#include <cstdint>

// Problem constants
#define BATCH 4096
#define DIN   512
#define DH    256
#define DG    128
#define NH    8
#define NTOT  3328   // DH + NH*DH + NH*DG = 256 + 2048 + 1024

typedef __bf16 bf16x8 __attribute__((ext_vector_type(8)));
typedef float  f32x4  __attribute__((ext_vector_type(4)));

__device__ __forceinline__ unsigned short f2bf(float f) {
    union { float f; uint32_t u; } v; v.f = f;
    uint32_t u = v.u;
    u += 0x7fffu + ((u >> 16) & 1u);   // RNE; inputs are finite normals
    return (unsigned short)(u >> 16);
}

// async global->LDS, 16B per lane; lds base must be wave-uniform (dest = base + lane*16)
__device__ __forceinline__ void async16(const unsigned short* g, unsigned short* l) {
    __builtin_amdgcn_global_load_lds(
        (const __attribute__((address_space(1))) unsigned int*)(uintptr_t)g,
        (__attribute__((address_space(3))) unsigned int*)(uintptr_t)l,
        16, 0, 0);
}

// ---------------- prep: x (4096x512 f32) -> bf16 ----------------
__global__ void cvt_x(const float* __restrict__ x, unsigned short* __restrict__ xb) {
    int i = (blockIdx.x * 256 + threadIdx.x) * 4;
    float4 v = *(const float4*)(x + i);
    ushort4 o;
    o.x = f2bf(v.x); o.y = f2bf(v.y); o.z = f2bf(v.z); o.w = f2bf(v.w);
    *(ushort4*)(xb + i) = o;
}

// ---- prep: transpose/concat Wh,Wz1,Wz2 (K x n) -> Wt[3328][512] bf16 ----
__global__ void transpose_w(const float* __restrict__ Wh, const float* __restrict__ Wz1,
                            const float* __restrict__ Wz2, unsigned short* __restrict__ Wt) {
    __shared__ float tile[32][33];
    int n0 = blockIdx.x * 32;
    int k0 = blockIdx.y * 32;
    const float* W; int ldn, nl;
    if (n0 < 256)       { W = Wh;  ldn = 256;  nl = n0; }
    else if (n0 < 2304) { W = Wz1; ldn = 2048; nl = n0 - 256; }
    else                { W = Wz2; ldn = 1024; nl = n0 - 2304; }
    int tx = threadIdx.x, ty = threadIdx.y;   // 32 x 8
    #pragma unroll
    for (int i = 0; i < 4; i++) {
        int kk = ty + i * 8;
        tile[kk][tx] = W[(size_t)(k0 + kk) * ldn + nl + tx];
    }
    __syncthreads();
    #pragma unroll
    for (int i = 0; i < 4; i++) {
        int nn = ty + i * 8;
        Wt[(size_t)(n0 + nn) * 512 + k0 + tx] = f2bf(tile[tx][nn]);
    }
}

// ------------- fused GEMM: Z[4096][3328] = xb @ Wt^T (bf16 MFMA) -------------
// 128x128 tile, 4 waves of 64x64, BK=32, async global_load_lds staging with
// XOR chunk swizzle (chunk stored at slot = src_chunk ^ (row&3)) so the
// forced-contiguous LDS layout still gives 2-way-max (free) ds_read_b128 banks.
__global__ __launch_bounds__(256) void gemm_kernel(const unsigned short* __restrict__ xb,
                                                   const unsigned short* __restrict__ Wt,
                                                   float* __restrict__ Z) {
    __shared__ unsigned short As[128 * 32];  // 8KB, unpadded (required by global_load_lds)
    __shared__ unsigned short Bs[128 * 32];
    const int m0 = blockIdx.y * 128;
    const int n0 = blockIdx.x * 128;
    const int t = threadIdx.x;
    const int w = t >> 6, lane = t & 63;
    const int wm = (w >> 1) * 64, wn = (w & 1) * 64;
    const int lrow = lane & 15, q = lane >> 4;
    const int swz = q ^ (lrow & 3);          // physical chunk for logical chunk q

    f32x4 acc[4][4] = {};

    for (int k0 = 0; k0 < DIN; k0 += 32) {
        __syncthreads();   // protect LDS from previous iteration's readers
        #pragma unroll
        for (int j = 0; j < 2; j++) {
            int gidx = (w * 2 + j) * 64 + lane;     // chunk id 0..511
            int row = gidx >> 2, slot = gidx & 3;
            int src = slot ^ (row & 3);
            const unsigned short* ga = xb + (size_t)(m0 + row) * DIN + k0 + src * 8;
            const unsigned short* gb = Wt + (size_t)(n0 + row) * DIN + k0 + src * 8;
            async16(ga, As + (w * 2 + j) * 512);
            async16(gb, Bs + (w * 2 + j) * 512);
        }
        __syncthreads();   // drains vmcnt -> staged data visible
        bf16x8 af[4], bfr[4];
        #pragma unroll
        for (int i = 0; i < 4; i++)
            af[i] = *reinterpret_cast<const bf16x8*>(As + (wm + i * 16 + lrow) * 32 + swz * 8);
        #pragma unroll
        for (int j = 0; j < 4; j++)
            bfr[j] = *reinterpret_cast<const bf16x8*>(Bs + (wn + j * 16 + lrow) * 32 + swz * 8);
        #pragma unroll
        for (int i = 0; i < 4; i++)
            #pragma unroll
            for (int j = 0; j < 4; j++)
                acc[i][j] = __builtin_amdgcn_mfma_f32_16x16x32_bf16(af[i], bfr[j], acc[i][j], 0, 0, 0);
    }
    // C/D layout: col = lane&15, row = (lane>>4)*4 + reg
    #pragma unroll
    for (int i = 0; i < 4; i++)
        #pragma unroll
        for (int j = 0; j < 4; j++) {
            int col = n0 + wn + j * 16 + lrow;
            int rbase = m0 + wm + i * 16 + q * 4;
            #pragma unroll
            for (int r = 0; r < 4; r++)
                Z[(size_t)(rbase + r) * NTOT + col] = acc[i][j][r];
        }
}

// ------- per-batch: LN(relu(hpre+b)) -> h ; Gram-trick stats ; tanh pass ; y -------
// Identity: mu_g = z2_g . m1 / 256, E[w^2]_g = z2_g^T G z2_g / 256 with
// G = z1aug z1aug^T (z1aug has a ones row) -> no stats recompute pass.
__global__ __launch_bounds__(256) void attn_kernel(const float* __restrict__ Z,
                                                   const float* __restrict__ bh,
                                                   const float* __restrict__ lns,
                                                   const float* __restrict__ lnb,
                                                   float* __restrict__ h_out,
                                                   float* __restrict__ y_out) {
    __shared__ float z1s[9 * 256];   // rows 0..7 = z1 heads, row 8 = ones (9KB)
    __shared__ float z2s[NH * DG];   // 4KB
    __shared__ float hs[DH];         // 1KB
    __shared__ float GL[9][9];
    __shared__ float A2L[DG], B2L[DG];
    __shared__ float red[4][3];
    const int b = blockIdx.x;
    const int t = threadIdx.x;
    const int wv = t >> 6, lane = t & 63;
    const float* Zrow = Z + (size_t)b * NTOT;

    // ---- stage z1 (2048), z2 (1024), ones row ----
    {
        float4 v0 = *(const float4*)(Zrow + 256 + t * 4);
        float4 v1 = *(const float4*)(Zrow + 256 + 1024 + t * 4);
        float4 v2 = *(const float4*)(Zrow + 256 + 2048 + t * 4);
        *(float4*)(z1s + t * 4) = v0;
        *(float4*)(z1s + 1024 + t * 4) = v1;
        *(float4*)(z2s + t * 4) = v2;
        z1s[2048 + t] = 1.0f;
    }
    // ---- layernorm(relu(hpre + bh)) ----
    float v = fmaxf(Zrow[t] + bh[t], 0.0f);
    float s = v, sq = v * v;
    #pragma unroll
    for (int m = 32; m >= 1; m >>= 1) {
        s  += __shfl_xor(s,  m, 64);
        sq += __shfl_xor(sq, m, 64);
    }
    if (lane == 0) { red[wv][0] = s; red[wv][1] = sq; }
    __syncthreads();   // (#1) staging + LN partials visible
    s  = red[0][0] + red[1][0] + red[2][0] + red[3][0];
    sq = red[0][1] + red[1][1] + red[2][1] + red[3][1];
    float mu  = s * (1.0f / 256.0f);
    float var = sq * (1.0f / 256.0f) - mu * mu;
    float hval = (v - mu) * rsqrtf(var + 1e-6f) * lns[t] + lnb[t];
    hs[t] = hval;
    h_out[(size_t)b * DH + t] = hval;
    // Hsum partial (needed for y = Hsum - 2*sum(h/(1+e^2s)))
    float hp = hval;
    #pragma unroll
    for (int m = 32; m >= 1; m >>= 1) hp += __shfl_xor(hp, m, 64);
    if (lane == 0) red[wv][2] = hp;

    // ---- Gram: 44 pair-dots (h<=h'<=8, minus (8,8)); 11 per wave, 64-lane reduce ----
    {
        #pragma unroll
        for (int j = 0; j < 11; j++) {
            int task = wv * 11 + j;
            int h = 0, rem = task;
            while (rem >= 9 - h) { rem -= 9 - h; h++; }   // wave-uniform scalar loop
            int h2 = h + rem;
            float4 a = *(const float4*)(z1s + h  * 256 + lane * 4);
            float4 c = *(const float4*)(z1s + h2 * 256 + lane * 4);
            float p = a.x * c.x + a.y * c.y + a.z * c.z + a.w * c.w;
            #pragma unroll
            for (int m = 32; m >= 1; m >>= 1) p += __shfl_xor(p, m, 64);
            if (lane == 0) { GL[h][h2] = p; GL[h2][h] = p; }
        }
    }
    __syncthreads();   // (#2) GL, hs, Hsum partials visible
    float Hsum = red[0][2] + red[1][2] + red[2][2] + red[3][2];

    // ---- per-g stats from Gram (threads 0..127) ----
    if (t < DG) {
        float z2g[NH];
        #pragma unroll
        for (int h = 0; h < NH; h++) z2g[h] = z2s[h * DG + t];
        float mug = 0.f, qg = 0.f;
        #pragma unroll
        for (int h = 0; h < NH; h++) {
            mug += z2g[h] * GL[h][8];
            float inn = 0.f;
            #pragma unroll
            for (int h2 = 0; h2 < NH; h2++) inn += z2g[h2] * GL[h][h2];
            qg += z2g[h] * inn;
        }
        mug *= (1.0f / 256.0f);
        qg  *= (1.0f / 256.0f);
        float vg = fmaxf(qg - mug * mug, 0.0f);
        float inv = 1.0f / (sqrtf(vg) + 1e-6f);
        float A = 2.0f * inv;             // e = exp(A*w + B) = exp(2*(w-mu)*inv)
        A2L[t] = A;
        B2L[t] = -mug * A;
    }
    __syncthreads();   // (#3) A2L/B2L visible

    // ---- main pass: w recompute -> tanh -> y, thread tile 8g x 16d-chunks ----
    const int td = t & 15, tg = t >> 4;
    const int g0 = tg * 8;
    float z2r[NH][8], A2r[8], B2r[8];
    #pragma unroll
    for (int h = 0; h < NH; h++) {
        float4 a = *(const float4*)(z2s + h * DG + g0);
        float4 c = *(const float4*)(z2s + h * DG + g0 + 4);
        z2r[h][0] = a.x; z2r[h][1] = a.y; z2r[h][2] = a.z; z2r[h][3] = a.w;
        z2r[h][4] = c.x; z2r[h][5] = c.y; z2r[h][6] = c.z; z2r[h][7] = c.w;
    }
    #pragma unroll
    for (int gi = 0; gi < 8; gi++) { A2r[gi] = A2L[g0 + gi]; B2r[gi] = B2L[g0 + gi]; }

    float yn[8] = {0,0,0,0,0,0,0,0};
    #pragma unroll
    for (int c = 0; c < 4; c++) {
        int dbase = c * 64 + td * 4;
        float z1a[NH][4];
        #pragma unroll
        for (int h = 0; h < NH; h++) {
            float4 zv = *(const float4*)(z1s + h * 256 + dbase);
            z1a[h][0] = zv.x; z1a[h][1] = zv.y; z1a[h][2] = zv.z; z1a[h][3] = zv.w;
        }
        float4 hvv = *(const float4*)(hs + dbase);
        float ha[4] = {hvv.x, hvv.y, hvv.z, hvv.w};
        #pragma unroll
        for (int gi = 0; gi < 8; gi++)
            #pragma unroll
            for (int e = 0; e < 4; e++) {
                float wv_ = z2r[0][gi] * z1a[0][e];
                #pragma unroll
                for (int h = 1; h < NH; h++) wv_ = fmaf(z2r[h][gi], z1a[h][e], wv_);
                float ex = __expf(fmaf(wv_, A2r[gi], B2r[gi]));
                yn[gi] = fmaf(ha[e], __builtin_amdgcn_rcpf(ex + 1.0f), yn[gi]);
            }
    }
    #pragma unroll
    for (int m = 1; m <= 8; m <<= 1)
        #pragma unroll
        for (int gi = 0; gi < 8; gi++)
            yn[gi] += __shfl_xor(yn[gi], m, 64);
    if (td == 0) {
        float4 o0 = {Hsum - 2.0f * yn[0], Hsum - 2.0f * yn[1],
                     Hsum - 2.0f * yn[2], Hsum - 2.0f * yn[3]};
        float4 o1 = {Hsum - 2.0f * yn[4], Hsum - 2.0f * yn[5],
                     Hsum - 2.0f * yn[6], Hsum - 2.0f * yn[7]};
        *(float4*)(y_out + (size_t)b * DG + g0)     = o0;
        *(float4*)(y_out + (size_t)b * DG + g0 + 4) = o1;
    }
}

extern "C" void kernel_launch(void* const* d_in, const int* in_sizes, int n_in,
                              void* d_out, int out_size, void* d_ws, size_t ws_size,
                              hipStream_t stream) {
    const float* x   = (const float*)d_in[0];
    const float* Wh  = (const float*)d_in[1];
    const float* bh  = (const float*)d_in[2];
    const float* Wz1 = (const float*)d_in[3];
    const float* Wz2 = (const float*)d_in[4];
    const float* lns = (const float*)d_in[5];
    const float* lnb = (const float*)d_in[6];
    float* h_out = (float*)d_out;
    float* y_out = h_out + (size_t)BATCH * DH;

    char* ws = (char*)d_ws;
    float*          Z  = (float*)ws;                        // 54,525,952 B
    unsigned short* xb = (unsigned short*)(ws + 54525952);  //  4,194,304 B
    unsigned short* Wt = (unsigned short*)(ws + 58720256);  //  3,407,872 B

    cvt_x      <<<2048, 256, 0, stream>>>(x, xb);
    transpose_w<<<dim3(104, 16), dim3(32, 8), 0, stream>>>(Wh, Wz1, Wz2, Wt);
    gemm_kernel<<<dim3(NTOT / 128, BATCH / 128), 256, 0, stream>>>(xb, Wt, Z);
    attn_kernel<<<BATCH, 256, 0, stream>>>(Z, bh, lns, lnb, h_out, y_out);
}

// Round 3
// 155.449 us; speedup vs baseline: 1.9233x; 1.2535x over previous
//
#include <hip/hip_runtime.h>
#include <hip/hip_bf16.h>
#include <cstdint>

// Problem constants
#define BATCH 4096
#define DIN   512
#define DH    256
#define DG    128
#define NH    8
#define NTOT  3328   // DH + NH*DH + NH*DG = 256 + 2048 + 1024
#define S1    264    // padded fp32 row stride for z1 LDS (bank-spread, %4==0)

typedef __bf16 bf16x8 __attribute__((ext_vector_type(8)));
typedef float  f32x4  __attribute__((ext_vector_type(4)));

__device__ __forceinline__ unsigned short f2bf(float f) {
    union { float f; uint32_t u; } v; v.f = f;
    uint32_t u = v.u;
    u += 0x7fffu + ((u >> 16) & 1u);   // RNE; inputs are finite normals
    return (unsigned short)(u >> 16);
}

// async global->LDS, 16B per lane; dest = wave-uniform base + lane*16
__device__ __forceinline__ void async16(const unsigned short* g, unsigned short* l) {
    __builtin_amdgcn_global_load_lds(
        (const __attribute__((address_space(1))) unsigned int*)(uintptr_t)g,
        (__attribute__((address_space(3))) unsigned int*)(uintptr_t)l,
        16, 0, 0);
}

// ---------------- prep: x (4096x512 f32) -> bf16 ----------------
__global__ void cvt_x(const float* __restrict__ x, unsigned short* __restrict__ xb) {
    int i = (blockIdx.x * 256 + threadIdx.x) * 4;
    float4 v = *(const float4*)(x + i);
    ushort4 o;
    o.x = f2bf(v.x); o.y = f2bf(v.y); o.z = f2bf(v.z); o.w = f2bf(v.w);
    *(ushort4*)(xb + i) = o;
}

// ---- prep: transpose/concat Wh,Wz1,Wz2 (K x n) -> Wt[3328][512] bf16 ----
__global__ void transpose_w(const float* __restrict__ Wh, const float* __restrict__ Wz1,
                            const float* __restrict__ Wz2, unsigned short* __restrict__ Wt) {
    __shared__ float tile[32][33];
    int n0 = blockIdx.x * 32;
    int k0 = blockIdx.y * 32;
    const float* W; int ldn, nl;
    if (n0 < 256)       { W = Wh;  ldn = 256;  nl = n0; }
    else if (n0 < 2304) { W = Wz1; ldn = 2048; nl = n0 - 256; }
    else                { W = Wz2; ldn = 1024; nl = n0 - 2304; }
    int tx = threadIdx.x, ty = threadIdx.y;   // 32 x 8
    #pragma unroll
    for (int i = 0; i < 4; i++) {
        int kk = ty + i * 8;
        tile[kk][tx] = W[(size_t)(k0 + kk) * ldn + nl + tx];
    }
    __syncthreads();
    #pragma unroll
    for (int i = 0; i < 4; i++) {
        int nn = ty + i * 8;
        Wt[(size_t)(n0 + nn) * 512 + k0 + tx] = f2bf(tile[tx][nn]);
    }
}

// ------------- fused GEMM: Z[4096][3328] = xb @ Wt^T (bf16 MFMA) -------------
// 128x128 tile, 4 waves of 64x64, BK=64 (half the barriers of BK=32),
// async global_load_lds with 8-chunk XOR swizzle -> 2-way-free ds_read banks.
__global__ __launch_bounds__(256) void gemm_kernel(const unsigned short* __restrict__ xb,
                                                   const unsigned short* __restrict__ Wt,
                                                   float* __restrict__ Z) {
    __shared__ unsigned short As[128 * 64];  // 16KB
    __shared__ unsigned short Bs[128 * 64];  // 16KB
    const int m0 = blockIdx.y * 128;
    const int n0 = blockIdx.x * 128;
    const int t = threadIdx.x;
    const int w = t >> 6, lane = t & 63;
    const int wm = (w >> 1) * 64, wn = (w & 1) * 64;
    const int lrow = lane & 15, q = lane >> 4;

    f32x4 acc[4][4] = {};

    for (int k0 = 0; k0 < DIN; k0 += 64) {
        __syncthreads();
        #pragma unroll
        for (int j = 0; j < 4; j++) {
            int gidx = (w * 4 + j) * 64 + lane;       // chunk id 0..1023 (16B chunks)
            int row = gidx >> 3, slot = gidx & 7;     // 128B row = 8 chunks
            int src = slot ^ (row & 7);
            const unsigned short* ga = xb + (size_t)(m0 + row) * DIN + k0 + src * 8;
            const unsigned short* gb = Wt + (size_t)(n0 + row) * DIN + k0 + src * 8;
            async16(ga, As + (w * 4 + j) * 512);
            async16(gb, Bs + (w * 4 + j) * 512);
        }
        __syncthreads();   // drains vmcnt -> staged data visible
        #pragma unroll
        for (int ks = 0; ks < 2; ks++) {
            bf16x8 af[4], bfr[4];
            #pragma unroll
            for (int i = 0; i < 4; i++) {
                int row = wm + i * 16 + lrow;
                int phys = (ks * 4 + q) ^ (row & 7);
                af[i] = *reinterpret_cast<const bf16x8*>(As + row * 64 + phys * 8);
            }
            #pragma unroll
            for (int j = 0; j < 4; j++) {
                int row = wn + j * 16 + lrow;
                int phys = (ks * 4 + q) ^ (row & 7);
                bfr[j] = *reinterpret_cast<const bf16x8*>(Bs + row * 64 + phys * 8);
            }
            #pragma unroll
            for (int i = 0; i < 4; i++)
                #pragma unroll
                for (int j = 0; j < 4; j++)
                    acc[i][j] = __builtin_amdgcn_mfma_f32_16x16x32_bf16(af[i], bfr[j], acc[i][j], 0, 0, 0);
        }
    }
    // C/D layout: col = lane&15, row = (lane>>4)*4 + reg
    #pragma unroll
    for (int i = 0; i < 4; i++)
        #pragma unroll
        for (int j = 0; j < 4; j++) {
            int col = n0 + wn + j * 16 + lrow;
            int rbase = m0 + wm + i * 16 + q * 4;
            #pragma unroll
            for (int r = 0; r < 4; r++)
                Z[(size_t)(rbase + r) * NTOT + col] = acc[i][j][r];
        }
}

// ------- per-batch: LN -> h ; Gram stats ; MFMA-folded standardize+tanh ; y -------
// w-mu = sum_h z2[h][g]*(z1[h][d]-z1bar[h]);  s2 = (w-mu)*2*log2e/(std+eps) comes
// straight out of MFMA with A = z2*A2 (bf16), B = centered z1 (bf16), K=8 real
// k-slots (quads 1-3 read a shared 16B zero pad -> address select, no divergence).
// Then y_g = Hsum - 2*sum_d h_d * rcp(1 + exp2(s2)).
__global__ __launch_bounds__(256) void attn_kernel(const float* __restrict__ Z,
                                                   const float* __restrict__ bh,
                                                   const float* __restrict__ lns,
                                                   const float* __restrict__ lnb,
                                                   float* __restrict__ h_out,
                                                   float* __restrict__ y_out) {
    __shared__ float z1s[9 * S1];            // rows 0..7 = z1 heads (fp32), row 8 = ones
    __shared__ float z2s[NH * DG];           // raw z2 fp32 [h*128+g]
    __shared__ float hs[DH];
    __shared__ float GL[9][9];
    __shared__ unsigned short z1cb[DH * 8];  // centered z1, bf16, [d][h] 16B rows
    __shared__ unsigned short z2A[DG * 8];   // z2 * A2*, bf16, [g][h] 16B rows
    __shared__ unsigned short zpad[8];       // 16B of zeros (k-slot padding)
    __shared__ float red[4][3];
    const int b = blockIdx.x;
    const int t = threadIdx.x;
    const int wv = t >> 6, lane = t & 63;
    const float* Zrow = Z + (size_t)b * NTOT;

    // ---- stage ----
    {
        int i0 = t * 4;
        float4 v0 = *(const float4*)(Zrow + 256 + i0);
        float4 v1 = *(const float4*)(Zrow + 1280 + i0);
        float4 v2 = *(const float4*)(Zrow + 2304 + i0);
        *(float4*)(z1s + (i0 >> 8) * S1 + (i0 & 255)) = v0;
        int i1 = 1024 + i0;
        *(float4*)(z1s + (i1 >> 8) * S1 + (i1 & 255)) = v1;
        *(float4*)(z2s + i0) = v2;
        z1s[8 * S1 + t] = 1.0f;
        if (t < 8) zpad[t] = 0;
    }
    // ---- layernorm(relu(hpre + bh)) ----
    float v = fmaxf(Zrow[t] + bh[t], 0.0f);
    float s = v, sq = v * v;
    #pragma unroll
    for (int m = 32; m >= 1; m >>= 1) {
        s  += __shfl_xor(s,  m, 64);
        sq += __shfl_xor(sq, m, 64);
    }
    if (lane == 0) { red[wv][0] = s; red[wv][1] = sq; }
    __syncthreads();   // (#1) staging + LN partials
    s  = red[0][0] + red[1][0] + red[2][0] + red[3][0];
    sq = red[0][1] + red[1][1] + red[2][1] + red[3][1];
    float mu  = s * (1.0f / 256.0f);
    float var = sq * (1.0f / 256.0f) - mu * mu;
    float hval = (v - mu) * rsqrtf(var + 1e-6f) * lns[t] + lnb[t];
    hs[t] = hval;
    h_out[(size_t)b * DH + t] = hval;
    float hp = hval;
    #pragma unroll
    for (int m = 32; m >= 1; m >>= 1) hp += __shfl_xor(hp, m, 64);
    if (lane == 0) red[wv][2] = hp;

    // ---- Gram: 44 pair-dots over 9 rows (incl. ones row); 11 per wave ----
    #pragma unroll
    for (int j = 0; j < 11; j++) {
        int task = wv * 11 + j;
        int h = 0, rem = task;
        while (rem >= 9 - h) { rem -= 9 - h; h++; }
        int h2 = h + rem;
        float4 a = *(const float4*)(z1s + h  * S1 + lane * 4);
        float4 c = *(const float4*)(z1s + h2 * S1 + lane * 4);
        float p = a.x * c.x + a.y * c.y + a.z * c.z + a.w * c.w;
        #pragma unroll
        for (int m = 32; m >= 1; m >>= 1) p += __shfl_xor(p, m, 64);
        if (lane == 0) { GL[h][h2] = p; GL[h2][h] = p; }
    }
    __syncthreads();   // (#2) GL, hs, Hsum partials
    float Hsum = red[0][2] + red[1][2] + red[2][2] + red[3][2];

    // ---- build centered-z1 bf16 fragments (all threads, t = d) ----
    {
        unsigned short pk[8];
        #pragma unroll
        for (int h = 0; h < NH; h++) {
            float c = z1s[h * S1 + t] - GL[h][8] * (1.0f / 256.0f);
            pk[h] = f2bf(c);
        }
        ushort4 lo = {pk[0], pk[1], pk[2], pk[3]};
        ushort4 hi = {pk[4], pk[5], pk[6], pk[7]};
        *(ushort4*)(z1cb + t * 8)     = lo;
        *(ushort4*)(z1cb + t * 8 + 4) = hi;
    }
    // ---- stats + scaled-z2 bf16 fragments (t < 128, g = t) ----
    if (t < DG) {
        float z2g[NH];
        #pragma unroll
        for (int h = 0; h < NH; h++) z2g[h] = z2s[h * DG + t];
        float mug = 0.f, qg = 0.f;
        #pragma unroll
        for (int h = 0; h < NH; h++) {
            mug += z2g[h] * GL[h][8];
            float inn = 0.f;
            #pragma unroll
            for (int h2 = 0; h2 < NH; h2++) inn += z2g[h2] * GL[h][h2];
            qg += z2g[h] * inn;
        }
        mug *= (1.0f / 256.0f);
        qg  *= (1.0f / 256.0f);
        float vg = fmaxf(qg - mug * mug, 0.0f);
        float A = 2.0f * 1.4426950408889634f / (sqrtf(vg) + 1e-6f);
        unsigned short pk[8];
        #pragma unroll
        for (int h = 0; h < NH; h++) pk[h] = f2bf(z2g[h] * A);
        ushort4 lo = {pk[0], pk[1], pk[2], pk[3]};
        ushort4 hi = {pk[4], pk[5], pk[6], pk[7]};
        *(ushort4*)(z2A + t * 8)     = lo;
        *(ushort4*)(z2A + t * 8 + 4) = hi;
    }
    __syncthreads();   // (#3) fragments ready

    // ---- main: per wave 2 g-tiles of 16, loop 16 d-tiles ----
    const int lrow = lane & 15, q = lane >> 4;
    const unsigned short* bptr = (q == 0) ? (z1cb + lrow * 8) : zpad;
    const int binc = (q == 0) ? 128 : 0;             // halves per d-tile
    bf16x8 af[2];
    #pragma unroll
    for (int gt = 0; gt < 2; gt++) {
        const unsigned short* aptr = (q == 0) ? (z2A + (wv * 32 + gt * 16 + lrow) * 8) : zpad;
        af[gt] = *reinterpret_cast<const bf16x8*>(aptr);
    }
    f32x4 czero = {};
    float yn[2][4] = {};
    #pragma unroll 4
    for (int dt = 0; dt < 16; dt++) {
        bf16x8 bfr = *reinterpret_cast<const bf16x8*>(bptr + dt * binc);
        float hv = hs[dt * 16 + lrow];
        #pragma unroll
        for (int gt = 0; gt < 2; gt++) {
            f32x4 c = __builtin_amdgcn_mfma_f32_16x16x32_bf16(af[gt], bfr, czero, 0, 0, 0);
            #pragma unroll
            for (int r = 0; r < 4; r++) {
                float e = __builtin_amdgcn_exp2f(c[r]);
                yn[gt][r] = fmaf(hv, __builtin_amdgcn_rcpf(e + 1.0f), yn[gt][r]);
            }
        }
    }
    #pragma unroll
    for (int m = 1; m <= 8; m <<= 1)
        #pragma unroll
        for (int gt = 0; gt < 2; gt++)
            #pragma unroll
            for (int r = 0; r < 4; r++)
                yn[gt][r] += __shfl_xor(yn[gt][r], m, 64);
    if (lrow == 0) {
        #pragma unroll
        for (int gt = 0; gt < 2; gt++)
            #pragma unroll
            for (int r = 0; r < 4; r++)
                y_out[(size_t)b * DG + wv * 32 + gt * 16 + q * 4 + r] = Hsum - 2.0f * yn[gt][r];
    }
}

extern "C" void kernel_launch(void* const* d_in, const int* in_sizes, int n_in,
                              void* d_out, int out_size, void* d_ws, size_t ws_size,
                              hipStream_t stream) {
    const float* x   = (const float*)d_in[0];
    const float* Wh  = (const float*)d_in[1];
    const float* bh  = (const float*)d_in[2];
    const float* Wz1 = (const float*)d_in[3];
    const float* Wz2 = (const float*)d_in[4];
    const float* lns = (const float*)d_in[5];
    const float* lnb = (const float*)d_in[6];
    float* h_out = (float*)d_out;
    float* y_out = h_out + (size_t)BATCH * DH;

    char* ws = (char*)d_ws;
    float*          Z  = (float*)ws;                        // 54,525,952 B
    unsigned short* xb = (unsigned short*)(ws + 54525952);  //  4,194,304 B
    unsigned short* Wt = (unsigned short*)(ws + 58720256);  //  3,407,872 B

    cvt_x      <<<2048, 256, 0, stream>>>(x, xb);
    transpose_w<<<dim3(104, 16), dim3(32, 8), 0, stream>>>(Wh, Wz1, Wz2, Wt);
    gemm_kernel<<<dim3(NTOT / 128, BATCH / 128), 256, 0, stream>>>(xb, Wt, Z);
    attn_kernel<<<BATCH, 256, 0, stream>>>(Z, bh, lns, lnb, h_out, y_out);
}

// Round 5
// 151.553 us; speedup vs baseline: 1.9727x; 1.0257x over previous
//
#include <hip/hip_runtime.h>
#include <hip/hip_bf16.h>
#include <cstdint>

#define BATCH 4096
#define DIN   512
#define DH    256
#define DG    128
#define NH    8
#define NTOT  3328
#define S1    264    // padded f32 row stride for z1 LDS

typedef __bf16 bf16x8 __attribute__((ext_vector_type(8)));
typedef float  f32x4  __attribute__((ext_vector_type(4)));

__device__ __forceinline__ unsigned short f2bf(float f) {
    union { float f; uint32_t u; } v; v.f = f;
    uint32_t u = v.u;
    u += 0x7fffu + ((u >> 16) & 1u);
    return (unsigned short)(u >> 16);
}
__device__ __forceinline__ float bf2f(unsigned short s) {
    union { uint32_t u; float f; } v; v.u = ((uint32_t)s) << 16;
    return v.f;
}
__device__ __forceinline__ void bf8_to_f8(uint4 u, float4& a, float4& b) {
    a.x = bf2f((unsigned short)(u.x & 0xffff)); a.y = bf2f((unsigned short)(u.x >> 16));
    a.z = bf2f((unsigned short)(u.y & 0xffff)); a.w = bf2f((unsigned short)(u.y >> 16));
    b.x = bf2f((unsigned short)(u.z & 0xffff)); b.y = bf2f((unsigned short)(u.z >> 16));
    b.z = bf2f((unsigned short)(u.w & 0xffff)); b.w = bf2f((unsigned short)(u.w >> 16));
}

__device__ __forceinline__ void async16(const unsigned short* g, unsigned short* l) {
    __builtin_amdgcn_global_load_lds(
        (const __attribute__((address_space(1))) unsigned int*)(uintptr_t)g,
        (__attribute__((address_space(3))) unsigned int*)(uintptr_t)l,
        16, 0, 0);
}

// ---------------- merged prep: cvt_x + transpose/concat weights ----------------
__global__ __launch_bounds__(256) void prep_kernel(const float* __restrict__ x,
                                                   const float* __restrict__ Wh,
                                                   const float* __restrict__ Wz1,
                                                   const float* __restrict__ Wz2,
                                                   unsigned short* __restrict__ xb,
                                                   unsigned short* __restrict__ Wt) {
    __shared__ float tile[32][33];
    int bid = blockIdx.x;
    int t = threadIdx.x;
    if (bid < 2048) {
        int i = (bid * 256 + t) * 4;
        float4 v = *(const float4*)(x + i);
        ushort4 o;
        o.x = f2bf(v.x); o.y = f2bf(v.y); o.z = f2bf(v.z); o.w = f2bf(v.w);
        *(ushort4*)(xb + i) = o;
        return;
    }
    int b2 = bid - 2048;
    int n0 = (b2 % 104) * 32;
    int k0 = (b2 / 104) * 32;
    const float* W; int ldn, nl;
    if (n0 < 256)       { W = Wh;  ldn = 256;  nl = n0; }
    else if (n0 < 2304) { W = Wz1; ldn = 2048; nl = n0 - 256; }
    else                { W = Wz2; ldn = 1024; nl = n0 - 2304; }
    int tx = t & 31, ty = t >> 5;
    #pragma unroll
    for (int i = 0; i < 4; i++) {
        int kk = ty + i * 8;
        tile[kk][tx] = W[(size_t)(k0 + kk) * ldn + nl + tx];
    }
    __syncthreads();
    #pragma unroll
    for (int i = 0; i < 4; i++) {
        int nn = ty + i * 8;
        Wt[(size_t)(n0 + nn) * 512 + k0 + tx] = f2bf(tile[tx][nn]);
    }
}

// ------------- fused GEMM: Zb[4096][3328](bf16) = xb @ Wt^T -------------
__global__ __launch_bounds__(256) void gemm_kernel(const unsigned short* __restrict__ xb,
                                                   const unsigned short* __restrict__ Wt,
                                                   unsigned short* __restrict__ Zb) {
    __shared__ unsigned short As[128 * 64];
    __shared__ unsigned short Bs[128 * 64];
    const int m0 = blockIdx.y * 128;
    const int n0 = blockIdx.x * 128;
    const int t = threadIdx.x;
    const int w = t >> 6, lane = t & 63;
    const int wm = (w >> 1) * 64, wn = (w & 1) * 64;
    const int lrow = lane & 15, q = lane >> 4;

    f32x4 acc[4][4] = {};

    for (int k0 = 0; k0 < DIN; k0 += 64) {
        __syncthreads();
        #pragma unroll
        for (int j = 0; j < 4; j++) {
            int gidx = (w * 4 + j) * 64 + lane;
            int row = gidx >> 3, slot = gidx & 7;
            int src = slot ^ (row & 7);
            const unsigned short* ga = xb + (size_t)(m0 + row) * DIN + k0 + src * 8;
            const unsigned short* gb = Wt + (size_t)(n0 + row) * DIN + k0 + src * 8;
            async16(ga, As + (w * 4 + j) * 512);
            async16(gb, Bs + (w * 4 + j) * 512);
        }
        __syncthreads();
        #pragma unroll
        for (int ks = 0; ks < 2; ks++) {
            bf16x8 af[4], bfr[4];
            #pragma unroll
            for (int i = 0; i < 4; i++) {
                int row = wm + i * 16 + lrow;
                int phys = (ks * 4 + q) ^ (row & 7);
                af[i] = *reinterpret_cast<const bf16x8*>(As + row * 64 + phys * 8);
            }
            #pragma unroll
            for (int j = 0; j < 4; j++) {
                int row = wn + j * 16 + lrow;
                int phys = (ks * 4 + q) ^ (row & 7);
                bfr[j] = *reinterpret_cast<const bf16x8*>(Bs + row * 64 + phys * 8);
            }
            #pragma unroll
            for (int i = 0; i < 4; i++)
                #pragma unroll
                for (int j = 0; j < 4; j++)
                    acc[i][j] = __builtin_amdgcn_mfma_f32_16x16x32_bf16(af[i], bfr[j], acc[i][j], 0, 0, 0);
        }
    }
    #pragma unroll
    for (int i = 0; i < 4; i++)
        #pragma unroll
        for (int j = 0; j < 4; j++) {
            int col = n0 + wn + j * 16 + lrow;
            int rbase = m0 + wm + i * 16 + q * 4;
            #pragma unroll
            for (int r = 0; r < 4; r++)
                Zb[(size_t)(rbase + r) * NTOT + col] = f2bf(acc[i][j][r]);
        }
}

// ------- per-batch (R3-proven body, bf16-input shims): LN -> h ; Gram ; MFMA tanh ; y -------
__global__ __launch_bounds__(256) void attn_kernel(const unsigned short* __restrict__ Zb,
                                                   const float* __restrict__ bh,
                                                   const float* __restrict__ lns,
                                                   const float* __restrict__ lnb,
                                                   float* __restrict__ h_out,
                                                   float* __restrict__ y_out) {
    __shared__ float z1s[9 * S1];            // rows 0..7 = z1 heads (f32), row 8 = ones
    __shared__ float z2s[NH * DG];           // raw z2 f32 [h*128+g]
    __shared__ float hs[DH];
    __shared__ float GL[9][9];
    __shared__ unsigned short z1cb[DH * 8];  // centered z1, bf16, [d][h]
    __shared__ unsigned short z2A[DG * 8];   // z2 * A, bf16, [g][h]
    __shared__ unsigned short zpad[8];
    __shared__ float red[4][3];
    const int b = blockIdx.x;
    const int t = threadIdx.x;
    const int wv = t >> 6, lane = t & 63;
    const unsigned short* Zrow = Zb + (size_t)b * NTOT;

    // ---- stage: bf16 -> f32 LDS (R3 layout) ----
    {
        uint4 v1 = *(const uint4*)(Zrow + 256 + t * 8);
        float4 a, c; bf8_to_f8(v1, a, c);
        int hh = t >> 5, d0 = (t & 31) * 8;
        *(float4*)(z1s + hh * S1 + d0)     = a;
        *(float4*)(z1s + hh * S1 + d0 + 4) = c;
        if (t < 128) {
            uint4 v2 = *(const uint4*)(Zrow + 2304 + t * 8);
            float4 e, f; bf8_to_f8(v2, e, f);
            *(float4*)(z2s + t * 8)     = e;
            *(float4*)(z2s + t * 8 + 4) = f;
        }
        z1s[8 * S1 + t] = 1.0f;
        if (t < 8) zpad[t] = 0;
    }
    // ---- layernorm(relu(hpre + bh)) — hpre read directly from global ----
    float v = fmaxf(bf2f(Zrow[t]) + bh[t], 0.0f);
    float s = v, sq = v * v;
    #pragma unroll
    for (int m = 32; m >= 1; m >>= 1) {
        s  += __shfl_xor(s,  m, 64);
        sq += __shfl_xor(sq, m, 64);
    }
    if (lane == 0) { red[wv][0] = s; red[wv][1] = sq; }
    __syncthreads();   // (#1) staging + LN partials
    s  = red[0][0] + red[1][0] + red[2][0] + red[3][0];
    sq = red[0][1] + red[1][1] + red[2][1] + red[3][1];
    float mu  = s * (1.0f / 256.0f);
    float var = sq * (1.0f / 256.0f) - mu * mu;
    float hval = (v - mu) * rsqrtf(var + 1e-6f) * lns[t] + lnb[t];
    hs[t] = hval;
    h_out[(size_t)b * DH + t] = hval;
    float hp = hval;
    #pragma unroll
    for (int m = 32; m >= 1; m >>= 1) hp += __shfl_xor(hp, m, 64);
    if (lane == 0) red[wv][2] = hp;

    // ---- Gram: 44 pair-dots over 9 rows (incl. ones row); 11 per wave ----
    #pragma unroll
    for (int j = 0; j < 11; j++) {
        int task = wv * 11 + j;
        int h = 0, rem = task;
        while (rem >= 9 - h) { rem -= 9 - h; h++; }
        int h2 = h + rem;
        float4 a = *(const float4*)(z1s + h  * S1 + lane * 4);
        float4 c = *(const float4*)(z1s + h2 * S1 + lane * 4);
        float p = a.x * c.x + a.y * c.y + a.z * c.z + a.w * c.w;
        #pragma unroll
        for (int m = 32; m >= 1; m >>= 1) p += __shfl_xor(p, m, 64);
        if (lane == 0) { GL[h][h2] = p; GL[h2][h] = p; }
    }
    __syncthreads();   // (#2) GL, hs, Hsum partials
    float Hsum = red[0][2] + red[1][2] + red[2][2] + red[3][2];

    // ---- build centered-z1 bf16 fragments (t = d) ----
    {
        unsigned short pk[8];
        #pragma unroll
        for (int h = 0; h < NH; h++) {
            float c = z1s[h * S1 + t] - GL[h][8] * (1.0f / 256.0f);
            pk[h] = f2bf(c);
        }
        ushort4 lo = {pk[0], pk[1], pk[2], pk[3]};
        ushort4 hi = {pk[4], pk[5], pk[6], pk[7]};
        *(ushort4*)(z1cb + t * 8)     = lo;
        *(ushort4*)(z1cb + t * 8 + 4) = hi;
    }
    // ---- stats + scaled-z2 bf16 fragments (t < 128, g = t) ----
    if (t < DG) {
        float z2g[NH];
        #pragma unroll
        for (int h = 0; h < NH; h++) z2g[h] = z2s[h * DG + t];
        float mug = 0.f, qg = 0.f;
        #pragma unroll
        for (int h = 0; h < NH; h++) {
            mug += z2g[h] * GL[h][8];
            float inn = 0.f;
            #pragma unroll
            for (int h2 = 0; h2 < NH; h2++) inn += z2g[h2] * GL[h][h2];
            qg += z2g[h] * inn;
        }
        mug *= (1.0f / 256.0f);
        qg  *= (1.0f / 256.0f);
        float vg = fmaxf(qg - mug * mug, 0.0f);
        float A = 2.0f * 1.4426950408889634f / (sqrtf(vg) + 1e-6f);
        unsigned short pk[8];
        #pragma unroll
        for (int h = 0; h < NH; h++) pk[h] = f2bf(z2g[h] * A);
        ushort4 lo = {pk[0], pk[1], pk[2], pk[3]};
        ushort4 hi = {pk[4], pk[5], pk[6], pk[7]};
        *(ushort4*)(z2A + t * 8)     = lo;
        *(ushort4*)(z2A + t * 8 + 4) = hi;
    }
    __syncthreads();   // (#3) fragments ready

    // ---- main: per wave 2 g-tiles of 16, loop 16 d-tiles ----
    const int lrow = lane & 15, q = lane >> 4;
    const unsigned short* bptr = (q == 0) ? (z1cb + lrow * 8) : zpad;
    const int binc = (q == 0) ? 128 : 0;
    bf16x8 af[2];
    #pragma unroll
    for (int gt = 0; gt < 2; gt++) {
        const unsigned short* aptr = (q == 0) ? (z2A + (wv * 32 + gt * 16 + lrow) * 8) : zpad;
        af[gt] = *reinterpret_cast<const bf16x8*>(aptr);
    }
    f32x4 czero = {};
    float yn[2][4] = {};
    #pragma unroll 4
    for (int dt = 0; dt < 16; dt++) {
        bf16x8 bfr = *reinterpret_cast<const bf16x8*>(bptr + dt * binc);
        float hv = hs[dt * 16 + lrow];
        #pragma unroll
        for (int gt = 0; gt < 2; gt++) {
            f32x4 c = __builtin_amdgcn_mfma_f32_16x16x32_bf16(af[gt], bfr, czero, 0, 0, 0);
            #pragma unroll
            for (int r = 0; r < 4; r++) {
                float e = __builtin_amdgcn_exp2f(c[r]);
                yn[gt][r] = fmaf(hv, __builtin_amdgcn_rcpf(e + 1.0f), yn[gt][r]);
            }
        }
    }
    #pragma unroll
    for (int m = 1; m <= 8; m <<= 1)
        #pragma unroll
        for (int gt = 0; gt < 2; gt++)
            #pragma unroll
            for (int r = 0; r < 4; r++)
                yn[gt][r] += __shfl_xor(yn[gt][r], m, 64);
    if (lrow == 0) {
        #pragma unroll
        for (int gt = 0; gt < 2; gt++)
            #pragma unroll
            for (int r = 0; r < 4; r++)
                y_out[(size_t)b * DG + wv * 32 + gt * 16 + q * 4 + r] = Hsum - 2.0f * yn[gt][r];
    }
}

extern "C" void kernel_launch(void* const* d_in, const int* in_sizes, int n_in,
                              void* d_out, int out_size, void* d_ws, size_t ws_size,
                              hipStream_t stream) {
    const float* x   = (const float*)d_in[0];
    const float* Wh  = (const float*)d_in[1];
    const float* bh  = (const float*)d_in[2];
    const float* Wz1 = (const float*)d_in[3];
    const float* Wz2 = (const float*)d_in[4];
    const float* lns = (const float*)d_in[5];
    const float* lnb = (const float*)d_in[6];
    float* h_out = (float*)d_out;
    float* y_out = h_out + (size_t)BATCH * DH;

    char* ws = (char*)d_ws;
    unsigned short* Zb = (unsigned short*)ws;               // 27,262,976 B
    unsigned short* xb = (unsigned short*)(ws + 27262976);  //  4,194,304 B
    unsigned short* Wt = (unsigned short*)(ws + 31457280);  //  3,407,872 B (~34.9 MB)

    prep_kernel<<<3712, 256, 0, stream>>>(x, Wh, Wz1, Wz2, xb, Wt);
    gemm_kernel<<<dim3(NTOT / 128, BATCH / 128), 256, 0, stream>>>(xb, Wt, Zb);
    attn_kernel<<<BATCH, 256, 0, stream>>>(Zb, bh, lns, lnb, h_out, y_out);
}